// Round 1
// baseline (438.067 us; speedup 1.0000x reference)
//
#include <hip/hip_runtime.h>

// EWMA: y[0]=x[0]; y[t] = a*x[t] + (1-a)*y[t-1], over (T=4096, 64, 256) fp32.
// Memory-bound scan. Time is chunked (L=256) across blocks; each chunk
// reconstructs its carry with a W=64 warm-up (error ~0.7^64 ~ 1e-10).
// float4 per thread -> 16B/lane coalesced. Grid 16x16 = 256 blocks (1/CU).

#define A_COEF 0.3f
#define B_COEF 0.7f

constexpr int T  = 4096;
constexpr int C4 = 4096;   // (64*256)/4 float4 columns per time step
constexpr int L  = 256;    // time chunk length per block
constexpr int W  = 64;     // warm-up steps (0.7^64 ~= 1.3e-10 attenuation)

__global__ __launch_bounds__(256) void ewma_kernel(const float4* __restrict__ x,
                                                   float4* __restrict__ y) {
    const int c  = blockIdx.x * 256 + threadIdx.x;  // float4 column 0..4095
    const int k  = blockIdx.y;                      // time chunk
    const int t0 = k * L;

    float4 carry;
    int t;
    if (k == 0) {
        carry = x[c];       // y[0] = x[0] exactly
        y[c]  = carry;
        t = 1;
    } else {
        const int ts = t0 - W;
        carry = x[(size_t)ts * C4 + c];             // approx y[ts] ~= x[ts]
        #pragma unroll 8
        for (int tt = ts + 1; tt < t0; ++tt) {
            float4 v = x[(size_t)tt * C4 + c];
            carry.x = fmaf(A_COEF, v.x, B_COEF * carry.x);
            carry.y = fmaf(A_COEF, v.y, B_COEF * carry.y);
            carry.z = fmaf(A_COEF, v.z, B_COEF * carry.z);
            carry.w = fmaf(A_COEF, v.w, B_COEF * carry.w);
        }
        t = t0;
    }

    const int tend = t0 + L;
    #pragma unroll 8
    for (; t < tend; ++t) {
        const size_t idx = (size_t)t * C4 + c;
        float4 v = x[idx];
        carry.x = fmaf(A_COEF, v.x, B_COEF * carry.x);
        carry.y = fmaf(A_COEF, v.y, B_COEF * carry.y);
        carry.z = fmaf(A_COEF, v.z, B_COEF * carry.z);
        carry.w = fmaf(A_COEF, v.w, B_COEF * carry.w);
        y[idx] = carry;
    }
}

extern "C" void kernel_launch(void* const* d_in, const int* in_sizes, int n_in,
                              void* d_out, int out_size, void* d_ws, size_t ws_size,
                              hipStream_t stream) {
    const float4* x = (const float4*)d_in[0];
    float4*       y = (float4*)d_out;
    dim3 grid(C4 / 256, T / L);   // (16, 16)
    ewma_kernel<<<grid, 256, 0, stream>>>(x, y);
}